// Round 4
// baseline (184.502 us; speedup 1.0000x reference)
//
#include <hip/hip_runtime.h>
#include <math.h>

typedef __attribute__((ext_vector_type(8)))  short short8;
typedef __attribute__((ext_vector_type(16))) float float16_t;

__device__ __forceinline__ short f2bf(float f) {          // RNE (prep only)
    union { float f; unsigned u; } c; c.f = f;
    unsigned u = c.u + 0x7fffu + ((c.u >> 16) & 1u);
    return (short)(u >> 16);
}
__device__ __forceinline__ unsigned fbits(float f) {
    union { float f; unsigned u; } c; c.f = f; return c.u;
}
__device__ __forceinline__ float16_t zero16() {
    float16_t z;
#pragma unroll
    for (int r = 0; r < 16; ++r) z[r] = 0.0f;
    return z;
}

// ---------------------------------------------------------------------------
// Prep (fp32 in -> bf16 out):  (unchanged from the verified 172us version)
//   Qz  = cos(x[...,:8])*cos(theta)            -> bf16 [32768][8]
//   W1z = [W1 | b1 | 0...] K-padded 8->16      -> bf16 [2048][16]
//   W2P = W2 in 32x32x16 MFMA B-fragment order:
//         [ntile(16)][kstep(128)][lane(64)][8]
//         element = W2[ntile*32 + (lane&31)][kstep*16 + (lane>>5)*8 + j]
// ---------------------------------------------------------------------------
__global__ __launch_bounds__(256) void prep_kernel(
    const float* __restrict__ x, const float* __restrict__ theta,
    const float* __restrict__ W1, const float* __restrict__ b1,
    const float* __restrict__ W2,
    short* __restrict__ W2P, short* __restrict__ Qz, short* __restrict__ W1z)
{
    int gid = blockIdx.x * 256 + threadIdx.x;
    if (gid < 131072) {                       // W2P
        int lane = gid & 63;
        int ks   = (gid >> 6) & 127;
        int nt   = gid >> 13;
        int n = nt * 32 + (lane & 31);
        int k = ks * 16 + (lane >> 5) * 8;
        const float4* p = (const float4*)(W2 + n * 2048 + k);
        float4 v0 = p[0], v1 = p[1];
        short8 o;
        o[0] = f2bf(v0.x); o[1] = f2bf(v0.y); o[2] = f2bf(v0.z); o[3] = f2bf(v0.w);
        o[4] = f2bf(v1.x); o[5] = f2bf(v1.y); o[6] = f2bf(v1.z); o[7] = f2bf(v1.w);
        *(short8*)(W2P + gid * 8) = o;
    } else if (gid < 131072 + 32768) {        // Qz
        int t = gid - 131072;
        const float4* xp = (const float4*)(x + t * 512);
        float4 x0 = xp[0], x1 = xp[1];
        float xv[8] = {x0.x, x0.y, x0.z, x0.w, x1.x, x1.y, x1.z, x1.w};
        short8 q;
#pragma unroll
        for (int c = 0; c < 8; ++c)
            q[c] = f2bf(cosf(xv[c]) * cosf(theta[c]));
        *(short8*)(Qz + t * 8) = q;
    } else if (gid < 131072 + 32768 + 2048) { // W1z rows: [W1(8) | b1 | 0x7]
        int f = gid - (131072 + 32768);
        const float4* wp = (const float4*)(W1 + f * 8);
        float4 w0 = wp[0], w1 = wp[1];
        short8 wv;
        wv[0] = f2bf(w0.x); wv[1] = f2bf(w0.y); wv[2] = f2bf(w0.z); wv[3] = f2bf(w0.w);
        wv[4] = f2bf(w1.x); wv[5] = f2bf(w1.y); wv[6] = f2bf(w1.z); wv[7] = f2bf(w1.w);
        short8 bz = {0,0,0,0,0,0,0,0};
        bz[0] = f2bf(b1[f]);                  // k=8 slot carries the bias
        *(short8*)(W1z + f * 16) = wv;
        *(short8*)(W1z + f * 16 + 8) = bz;
    }
}

// ---------------------------------------------------------------------------
// Stage 1: one 32f x 128m H^T sub-tile (4 chunks) into LDS chunk base cbase.
// Bias via the k=8 MFMA slot; relu + truncation-pack (v_perm) + b64 write.
// Identical math/layout to the verified kernel; cbase generalizes wx*4.
// ---------------------------------------------------------------------------
__device__ __forceinline__ void stage1_tile(
    short8 a1, const short8* qf, short* __restrict__ dst,
    int cbase, int wy, int lh, int l31)
{
#pragma unroll
    for (int i = 0; i < 2; ++i) {
        float16_t d1 = __builtin_amdgcn_mfma_f32_32x32x16_bf16(
            a1, qf[i], zero16(), 0, 0, 0);
        const int m = wy * 64 + i * 32 + l31;        // C/D col = m
#pragma unroll
        for (int g = 0; g < 4; ++g) {                // chunk c = cbase+g
            float v0 = fmaxf(d1[g * 4 + 0], 0.0f);
            float v1 = fmaxf(d1[g * 4 + 1], 0.0f);
            float v2 = fmaxf(d1[g * 4 + 2], 0.0f);
            float v3 = fmaxf(d1[g * 4 + 3], 0.0f);
            uint2 pp;                                 // truncation bf16 pack
            pp.x = __builtin_amdgcn_perm(fbits(v1), fbits(v0), 0x07060302u);
            pp.y = __builtin_amdgcn_perm(fbits(v3), fbits(v2), 0x07060302u);
            *(uint2*)(dst + (cbase + g) * 1024 + m * 8 + 4 * lh) = pp;
        }
    }
}

// ---------------------------------------------------------------------------
// Fused FFN v3 (BK=128): exactly round-0's proven geometry (512 blocks,
// 2 n-tiles x 256 m-tiles, per-wave 64m x 128n, 2 blocks/CU skew) but the
// K-tile per barrier doubles 64 -> 128: 16 iterations, 16 barriers (was 32),
// 68 MFMAs per wave between syncs (was 34). LDS 2 x 32KB ping-pong = 64KB
// (2 blocks/CU = 128KB <= 160KB). Stage-1 produces two 4-chunk groups per
// super-iter; B-fragments flow through two alternating register groups with
// >=16-MFMA prefetch distance throughout. Numerics identical.
// ---------------------------------------------------------------------------
__global__ __launch_bounds__(256, 2) void ffn_kernel(
    const short* __restrict__ Qz, const short* __restrict__ W1z,
    const short* __restrict__ W2P, const float* __restrict__ b2,
    float* __restrict__ out)
{
    __shared__ short Hs[2 * 16384];           // 2 x 32KB ping-pong, [c(16)][m][8]

    const int tid  = threadIdx.x;
    const int lane = tid & 63;
    const int w    = tid >> 6;                 // wave 0..3
    const int wy = w & 1, wx = w >> 1;         // m-half (64), n-half (128)
    const int l31 = lane & 31, lh = lane >> 5;
    const int bid = blockIdx.x;
    const int nt = bid & 1, mt = bid >> 1;
    const int m0 = mt * 128, n0 = nt * 256;

    // stage-1 B operand: Q rows (k 0..7) for lh=0; k=8 -> 1.0 for bias row
    short8 qf[2];
#pragma unroll
    for (int i = 0; i < 2; ++i) {
        short8 v = {0,0,0,0,0,0,0,0};
        if (lh == 0)
            v = *(const short8*)(Qz + (m0 + wy * 64 + i * 32 + l31) * 8);
        else
            v[0] = (short)0x3F80;              // bf16(1.0)
        qf[i] = v;
    }

    // loop-invariant lane offsets (short units)
    int w2off[4];
#pragma unroll
    for (int j = 0; j < 4; ++j)
        w2off[j] = (nt * 8 + wx * 4 + j) * 65536 + lane * 8;
    const int a1lo = (wx * 64 + l31) * 16 + lh * 8;   // f rows wx*64 + [0,32)
    const int a1hi = a1lo + 512;                      // f rows wx*64 + [32,64)

    float16_t acc[2][4];
#pragma unroll
    for (int i = 0; i < 2; ++i)
#pragma unroll
        for (int j = 0; j < 4; ++j) acc[i][j] = zero16();

    // ---- prologue ----
    const short* W2Pk = W2P;                   // advanced 4096/iter (= 8 ksteps)
    const short* W1za = W1z + 4096;            // rows for super kt+2, 2048/iter

    short8 bfvA[2][4], bfvB[2][4];
#pragma unroll
    for (int ks = 0; ks < 2; ++ks)
#pragma unroll
        for (int j = 0; j < 4; ++j)
            bfvA[ks][j] = *(const short8*)(W2Pk + w2off[j] + ks * 512);
    short8 a1nlo = *(const short8*)(W1z + 2048 + a1lo);  // super 1
    short8 a1nhi = *(const short8*)(W1z + 2048 + a1hi);
    {
        short8 lo = *(const short8*)(W1z + a1lo);
        short8 hi = *(const short8*)(W1z + a1hi);
        stage1_tile(lo, qf, Hs, wx * 8,     wy, lh, l31);   // H(0) -> half 0
        stage1_tile(hi, qf, Hs, wx * 8 + 4, wy, lh, l31);
    }
    __syncthreads();

    for (int kt = 0; kt < 16; ++kt) {
        short* wr = Hs + ((kt + 1) & 1) * 16384;
        const short* rd = Hs + (kt & 1) * 16384;

        // issue B chunks {2,3}; consumed after 16 MFMAs (phase 1)
#pragma unroll
        for (int ks = 0; ks < 2; ++ks)
#pragma unroll
            for (int j = 0; j < 4; ++j)
                bfvB[ks][j] = *(const short8*)(W2Pk + w2off[j] + (ks + 2) * 512);

        // stage 1 for super kt+1 (a1 pair already in registers)
        if (kt < 15) {
            stage1_tile(a1nlo, qf, wr, wx * 8,     wy, lh, l31);
            stage1_tile(a1nhi, qf, wr, wx * 8 + 4, wy, lh, l31);
        }
        if (kt < 14) {
            a1nlo = *(const short8*)(W1za + a1lo);           // super kt+2
            a1nhi = *(const short8*)(W1za + a1hi);
        }
        W1za += 2048;

        // phase 0: chunks {0,1} with bfvA
#pragma unroll
        for (int ks = 0; ks < 2; ++ks) {
            short8 af[2];
#pragma unroll
            for (int i = 0; i < 2; ++i)
                af[i] = *(const short8*)(rd + ((0 + ks) * 2 + lh) * 1024 +
                                         (wy * 64 + i * 32 + l31) * 8);
#pragma unroll
            for (int i = 0; i < 2; ++i)
#pragma unroll
                for (int j = 0; j < 4; ++j)
                    acc[i][j] = __builtin_amdgcn_mfma_f32_32x32x16_bf16(
                        af[i], bfvA[ks][j], acc[i][j], 0, 0, 0);
        }

        // refill bfvA <- chunks {4,5}; consumed after 16 MFMAs (phase 2)
#pragma unroll
        for (int ks = 0; ks < 2; ++ks)
#pragma unroll
            for (int j = 0; j < 4; ++j)
                bfvA[ks][j] = *(const short8*)(W2Pk + w2off[j] + (ks + 4) * 512);

        // phase 1: chunks {2,3} with bfvB
#pragma unroll
        for (int ks = 0; ks < 2; ++ks) {
            short8 af[2];
#pragma unroll
            for (int i = 0; i < 2; ++i)
                af[i] = *(const short8*)(rd + ((2 + ks) * 2 + lh) * 1024 +
                                         (wy * 64 + i * 32 + l31) * 8);
#pragma unroll
            for (int i = 0; i < 2; ++i)
#pragma unroll
                for (int j = 0; j < 4; ++j)
                    acc[i][j] = __builtin_amdgcn_mfma_f32_32x32x16_bf16(
                        af[i], bfvB[ks][j], acc[i][j], 0, 0, 0);
        }

        // refill bfvB <- chunks {6,7}; consumed after 16 MFMAs (phase 3)
#pragma unroll
        for (int ks = 0; ks < 2; ++ks)
#pragma unroll
            for (int j = 0; j < 4; ++j)
                bfvB[ks][j] = *(const short8*)(W2Pk + w2off[j] + (ks + 6) * 512);

        // phase 2: chunks {4,5} with bfvA
#pragma unroll
        for (int ks = 0; ks < 2; ++ks) {
            short8 af[2];
#pragma unroll
            for (int i = 0; i < 2; ++i)
                af[i] = *(const short8*)(rd + ((4 + ks) * 2 + lh) * 1024 +
                                         (wy * 64 + i * 32 + l31) * 8);
#pragma unroll
            for (int i = 0; i < 2; ++i)
#pragma unroll
                for (int j = 0; j < 4; ++j)
                    acc[i][j] = __builtin_amdgcn_mfma_f32_32x32x16_bf16(
                        af[i], bfvA[ks][j], acc[i][j], 0, 0, 0);
        }

        // prefetch next super's chunks {0,1}; crosses the barrier
        W2Pk += 4096;
        if (kt < 15) {
#pragma unroll
            for (int ks = 0; ks < 2; ++ks)
#pragma unroll
                for (int j = 0; j < 4; ++j)
                    bfvA[ks][j] = *(const short8*)(W2Pk + w2off[j] + ks * 512);
        }

        // phase 3: chunks {6,7} with bfvB
#pragma unroll
        for (int ks = 0; ks < 2; ++ks) {
            short8 af[2];
#pragma unroll
            for (int i = 0; i < 2; ++i)
                af[i] = *(const short8*)(rd + ((6 + ks) * 2 + lh) * 1024 +
                                         (wy * 64 + i * 32 + l31) * 8);
#pragma unroll
            for (int i = 0; i < 2; ++i)
#pragma unroll
                for (int j = 0; j < 4; ++j)
                    acc[i][j] = __builtin_amdgcn_mfma_f32_32x32x16_bf16(
                        af[i], bfvB[ks][j], acc[i][j], 0, 0, 0);
        }

        __syncthreads();
    }

    // ---- epilogue: out(fp32) = acc + b2 ----
#pragma unroll
    for (int j = 0; j < 4; ++j) {
        const int n = n0 + wx * 128 + j * 32 + l31;
        const float b2v = b2[n];
#pragma unroll
        for (int i = 0; i < 2; ++i) {
            const int base = (m0 + wy * 64 + i * 32 + 4 * lh) * 512 + n;
#pragma unroll
            for (int r = 0; r < 16; ++r) {
                const int off = ((r & 3) + 8 * (r >> 2)) * 512;
                out[base + off] = acc[i][j][r] + b2v;
            }
        }
    }
}

// ---------------------------------------------------------------------------
extern "C" void kernel_launch(void* const* d_in, const int* in_sizes, int n_in,
                              void* d_out, int out_size, void* d_ws, size_t ws_size,
                              hipStream_t stream)
{
    const float* x     = (const float*)d_in[0];  // [8,4096,512] fp32
    const float* theta = (const float*)d_in[1];  // [8] fp32
    const float* W1    = (const float*)d_in[2];  // [2048,8] fp32
    const float* b1    = (const float*)d_in[3];  // [2048] fp32
    const float* W2    = (const float*)d_in[4];  // [512,2048] fp32
    const float* b2    = (const float*)d_in[5];  // [512] fp32
    float* out = (float*)d_out;                  // [8,4096,512] fp32

    short* W2P = (short*)d_ws;                          // 2 MB
    short* Qz  = (short*)((char*)d_ws + 2097152);       // 512 KB
    short* W1z = (short*)((char*)d_ws + 2621440);       // 64 KB

    prep_kernel<<<648, 256, 0, stream>>>(x, theta, W1, b1, W2, W2P, Qz, W1z);
    ffn_kernel<<<512, 256, 0, stream>>>(Qz, W1z, W2P, b2, out);
}

// Round 5
// 177.017 us; speedup vs baseline: 1.0423x; 1.0423x over previous
//
#include <hip/hip_runtime.h>
#include <math.h>

typedef __attribute__((ext_vector_type(8)))  short short8;
typedef __attribute__((ext_vector_type(16))) float float16_t;

__device__ __forceinline__ short f2bf(float f) {          // RNE (prep only)
    union { float f; unsigned u; } c; c.f = f;
    unsigned u = c.u + 0x7fffu + ((c.u >> 16) & 1u);
    return (short)(u >> 16);
}
__device__ __forceinline__ unsigned fbits(float f) {
    union { float f; unsigned u; } c; c.f = f; return c.u;
}
__device__ __forceinline__ float16_t zero16() {
    float16_t z;
#pragma unroll
    for (int r = 0; r < 16; ++r) z[r] = 0.0f;
    return z;
}

// ---------------------------------------------------------------------------
// Prep (fp32 in -> bf16 out):
//   Qz  = cos(x[...,:8])*cos(theta)            -> bf16 [32768][8]
//   W1z = [W1 | b1 | 0...] K-padded 8->16      -> bf16 [2048][16]
//         (col 8 = b1[f]; ffn sets Q's k=8 input to 1.0 so the MFMA adds bias)
//   W2P = W2 in 32x32x16 MFMA B-fragment order:
//         W2P[((nt*128+ks)*64 + lh*32 + l31)*8 + j]
//           = bf16(W2[nt*32 + l31][ks*16 + lh*8 + j])
//   W2P branch remapped for coalesced READS: thread t handles row n = t>>8,
//   chunk c = t&255 (k8 = c*8) -> reads 32B contiguous (wave = 2KB
//   contiguous); writes 16B to the scattered fragment slot. Output layout
//   is bit-identical to the verified kernel (ks = c>>1, lh = c&1, l31 = n&31).
// ---------------------------------------------------------------------------
__global__ __launch_bounds__(256) void prep_kernel(
    const float* __restrict__ x, const float* __restrict__ theta,
    const float* __restrict__ W1, const float* __restrict__ b1,
    const float* __restrict__ W2,
    short* __restrict__ W2P, short* __restrict__ Qz, short* __restrict__ W1z)
{
    int gid = blockIdx.x * 256 + threadIdx.x;
    if (gid < 131072) {                       // W2P, coalesced-read mapping
        int n = gid >> 8;                     // W2 row 0..511
        int c = gid & 255;                    // 8-float chunk within the row
        const float4* p = (const float4*)(W2 + n * 2048 + c * 8);
        float4 v0 = p[0], v1 = p[1];
        short8 o;
        o[0] = f2bf(v0.x); o[1] = f2bf(v0.y); o[2] = f2bf(v0.z); o[3] = f2bf(v0.w);
        o[4] = f2bf(v1.x); o[5] = f2bf(v1.y); o[6] = f2bf(v1.z); o[7] = f2bf(v1.w);
        int dst = ((n >> 5) * 128 + (c >> 1)) * 512 + (c & 1) * 256 + (n & 31) * 8;
        *(short8*)(W2P + dst) = o;
    } else if (gid < 131072 + 32768) {        // Qz
        int t = gid - 131072;
        const float4* xp = (const float4*)(x + t * 512);
        float4 x0 = xp[0], x1 = xp[1];
        float xv[8] = {x0.x, x0.y, x0.z, x0.w, x1.x, x1.y, x1.z, x1.w};
        short8 q;
#pragma unroll
        for (int c = 0; c < 8; ++c)
            q[c] = f2bf(cosf(xv[c]) * cosf(theta[c]));
        *(short8*)(Qz + t * 8) = q;
    } else if (gid < 131072 + 32768 + 2048) { // W1z rows: [W1(8) | b1 | 0x7]
        int f = gid - (131072 + 32768);
        const float4* wp = (const float4*)(W1 + f * 8);
        float4 w0 = wp[0], w1 = wp[1];
        short8 wv;
        wv[0] = f2bf(w0.x); wv[1] = f2bf(w0.y); wv[2] = f2bf(w0.z); wv[3] = f2bf(w0.w);
        wv[4] = f2bf(w1.x); wv[5] = f2bf(w1.y); wv[6] = f2bf(w1.z); wv[7] = f2bf(w1.w);
        short8 bz = {0,0,0,0,0,0,0,0};
        bz[0] = f2bf(b1[f]);                  // k=8 slot carries the bias
        *(short8*)(W1z + f * 16) = wv;
        *(short8*)(W1z + f * 16 + 8) = bz;
    }
}

// ---------------------------------------------------------------------------
// Stage 1: H^T tile (64 f x 128 m) for one K-tile. Bias comes in via the
// k=8 MFMA slot; epilogue is relu + truncation-pack (v_perm) + b64 LDS write.
// (Verbatim from the verified 172us/77us kernel.)
// ---------------------------------------------------------------------------
__device__ __forceinline__ void stage1_tile(
    short8 a1, const short8* qf, short* __restrict__ dst,
    int wx, int wy, int lh, int l31)
{
#pragma unroll
    for (int i = 0; i < 2; ++i) {
        float16_t d1 = __builtin_amdgcn_mfma_f32_32x32x16_bf16(
            a1, qf[i], zero16(), 0, 0, 0);
        const int m = wy * 64 + i * 32 + l31;        // C/D col = m
#pragma unroll
        for (int g = 0; g < 4; ++g) {                // rows f = wx*32+4lh+8g+r
            float v0 = fmaxf(d1[g * 4 + 0], 0.0f);
            float v1 = fmaxf(d1[g * 4 + 1], 0.0f);
            float v2 = fmaxf(d1[g * 4 + 2], 0.0f);
            float v3 = fmaxf(d1[g * 4 + 3], 0.0f);
            uint2 pp;                                 // truncation bf16 pack
            pp.x = __builtin_amdgcn_perm(fbits(v1), fbits(v0), 0x07060302u);
            pp.y = __builtin_amdgcn_perm(fbits(v3), fbits(v2), 0x07060302u);
            *(uint2*)(dst + (wx * 4 + g) * 1024 + m * 8 + 4 * lh) = pp;
        }
    }
}

// ---------------------------------------------------------------------------
// Fused FFN (r0 structure, verified 77us): 512 blocks (2/CU), 128 tokens x
// 256 out-features, BK=64, ping-pong Hs, one barrier per K-iter. Software-
// pipelined global loads exactly as r0. Added: T5 s_setprio(1) around the
// two 16-MFMA stage-2 clusters — the 2 independently-barriered blocks/CU
// give wave role-diversity (one block in stage-1 VALU while the other is in
// stage-2 MFMA), the regime where priority arbitration pays.
// ---------------------------------------------------------------------------
__global__ __launch_bounds__(256, 2) void ffn_kernel(
    const short* __restrict__ Qz, const short* __restrict__ W1z,
    const short* __restrict__ W2P, const float* __restrict__ b2,
    float* __restrict__ out)
{
    __shared__ short Hs[2 * 8192];            // 2 x 16KB ping-pong, [c][m][8]

    const int tid  = threadIdx.x;
    const int lane = tid & 63;
    const int w    = tid >> 6;                 // wave 0..3
    const int wy = w & 1, wx = w >> 1;         // m-half (64), n-half (128)
    const int l31 = lane & 31, lh = lane >> 5;
    const int bid = blockIdx.x;
    const int nt = bid & 1, mt = bid >> 1;
    const int m0 = mt * 128, n0 = nt * 256;

    // stage-1 B operand: Q rows (k 0..7) for lh=0; k=8 -> 1.0 for bias row
    short8 qf[2];
#pragma unroll
    for (int i = 0; i < 2; ++i) {
        short8 v = {0,0,0,0,0,0,0,0};
        if (lh == 0)
            v = *(const short8*)(Qz + (m0 + wy * 64 + i * 32 + l31) * 8);
        else
            v[0] = (short)0x3F80;              // bf16(1.0)
        qf[i] = v;
    }

    // loop-invariant lane offsets (short units)
    int w2off[4];
#pragma unroll
    for (int j = 0; j < 4; ++j)
        w2off[j] = (nt * 8 + wx * 4 + j) * 65536 + lane * 8;
    const int a1off = (wx * 32 + l31) * 16 + lh * 8;

    float16_t acc[2][4];
#pragma unroll
    for (int i = 0; i < 2; ++i)
#pragma unroll
        for (int j = 0; j < 4; ++j) acc[i][j] = zero16();

    // ---- prologue ----
    const short* W2Pk = W2P;                   // advanced 2048/iter (= 1 kt)
    const short* W1za = W1z + 2048;            // rows for kt+2, 1024/iter

    short8 bfvA[2][4], bfvB[2][4];
#pragma unroll
    for (int ks = 0; ks < 2; ++ks)
#pragma unroll
        for (int j = 0; j < 4; ++j)
            bfvA[ks][j] = *(const short8*)(W2Pk + w2off[j] + ks * 512);
    short8 a1n = *(const short8*)(W1z + 1024 + a1off);   // W1 rows for kt=1
    {
        short8 a1_0 = *(const short8*)(W1z + a1off);
        stage1_tile(a1_0, qf, Hs, wx, wy, lh, l31);      // H(0) -> half 0
    }
    __syncthreads();

    for (int kt = 0; kt < 32; ++kt) {
        const int p = kt & 1;
        short* wr = Hs + (p ^ 1) * 8192;
        const short* rd = Hs + p * 8192;

        // issue B(kt, ks 2..3) now; consumed after 16 MFMAs of shadow
#pragma unroll
        for (int ks = 0; ks < 2; ++ks)
#pragma unroll
            for (int j = 0; j < 4; ++j)
                bfvB[ks][j] = *(const short8*)(W2Pk + w2off[j] + (ks + 2) * 512);

        // stage 1 for kt+1 (a1 already in registers -> starts immediately)
        if (kt < 31)
            stage1_tile(a1n, qf, wr, wx, wy, lh, l31);
        if (kt < 30)
            a1n = *(const short8*)(W1za + a1off);        // W1 rows for kt+2
        W1za += 1024;

        // stage 2, phase A: ks 0..1 with prefetched bfvA
        __builtin_amdgcn_s_setprio(1);
#pragma unroll
        for (int ks = 0; ks < 2; ++ks) {
            short8 af[2];
#pragma unroll
            for (int i = 0; i < 2; ++i)
                af[i] = *(const short8*)(rd + (ks * 2 + lh) * 1024 +
                                         (wy * 64 + i * 32 + l31) * 8);
#pragma unroll
            for (int i = 0; i < 2; ++i)
#pragma unroll
                for (int j = 0; j < 4; ++j)
                    acc[i][j] = __builtin_amdgcn_mfma_f32_32x32x16_bf16(
                        af[i], bfvA[ks][j], acc[i][j], 0, 0, 0);
        }
        __builtin_amdgcn_s_setprio(0);

        // prefetch B(kt+1, ks 0..1) across the barrier (bfvA regs now free)
        W2Pk += 2048;
        if (kt < 31) {
#pragma unroll
            for (int ks = 0; ks < 2; ++ks)
#pragma unroll
                for (int j = 0; j < 4; ++j)
                    bfvA[ks][j] = *(const short8*)(W2Pk + w2off[j] + ks * 512);
        }

        // stage 2, phase B: ks 2..3 with bfvB
        __builtin_amdgcn_s_setprio(1);
#pragma unroll
        for (int ks = 0; ks < 2; ++ks) {
            short8 af[2];
#pragma unroll
            for (int i = 0; i < 2; ++i)
                af[i] = *(const short8*)(rd + ((ks + 2) * 2 + lh) * 1024 +
                                         (wy * 64 + i * 32 + l31) * 8);
#pragma unroll
            for (int i = 0; i < 2; ++i)
#pragma unroll
                for (int j = 0; j < 4; ++j)
                    acc[i][j] = __builtin_amdgcn_mfma_f32_32x32x16_bf16(
                        af[i], bfvB[ks][j], acc[i][j], 0, 0, 0);
        }
        __builtin_amdgcn_s_setprio(0);

        __syncthreads();
    }

    // ---- epilogue: out(fp32) = acc + b2 ----
#pragma unroll
    for (int j = 0; j < 4; ++j) {
        const int n = n0 + wx * 128 + j * 32 + l31;
        const float b2v = b2[n];
#pragma unroll
        for (int i = 0; i < 2; ++i) {
            const int base = (m0 + wy * 64 + i * 32 + 4 * lh) * 512 + n;
#pragma unroll
            for (int r = 0; r < 16; ++r) {
                const int off = ((r & 3) + 8 * (r >> 2)) * 512;
                out[base + off] = acc[i][j][r] + b2v;
            }
        }
    }
}

// ---------------------------------------------------------------------------
extern "C" void kernel_launch(void* const* d_in, const int* in_sizes, int n_in,
                              void* d_out, int out_size, void* d_ws, size_t ws_size,
                              hipStream_t stream)
{
    const float* x     = (const float*)d_in[0];  // [8,4096,512] fp32
    const float* theta = (const float*)d_in[1];  // [8] fp32
    const float* W1    = (const float*)d_in[2];  // [2048,8] fp32
    const float* b1    = (const float*)d_in[3];  // [2048] fp32
    const float* W2    = (const float*)d_in[4];  // [512,2048] fp32
    const float* b2    = (const float*)d_in[5];  // [512] fp32
    float* out = (float*)d_out;                  // [8,4096,512] fp32

    short* W2P = (short*)d_ws;                          // 2 MB
    short* Qz  = (short*)((char*)d_ws + 2097152);       // 512 KB
    short* W1z = (short*)((char*)d_ws + 2621440);       // 64 KB

    prep_kernel<<<648, 256, 0, stream>>>(x, theta, W1, b1, W2, W2P, Qz, W1z);
    ffn_kernel<<<512, 256, 0, stream>>>(Qz, W1z, W2P, b2, out);
}